// Round 1
// baseline (2675.783 us; speedup 1.0000x reference)
//
#include <hip/hip_runtime.h>
#include <cstdint>
#include <cstddef>

#define Tn 2048
#define Bn 2
#define Hn 12
#define Cn 768
#define Ln 4
#define Vn 50257

typedef unsigned short ushort_t;
typedef __attribute__((ext_vector_type(8))) __bf16 bf16x8;
typedef __attribute__((ext_vector_type(4))) float f32x4;
typedef __attribute__((ext_vector_type(4))) int int4v;

__device__ inline unsigned short f2bf(float f) {
  unsigned int u = __float_as_uint(f);
  unsigned int r = (u + 0x7fffu + ((u >> 16) & 1u)) >> 16;
  return (unsigned short)r;
}

__device__ inline f32x4 zero4() { f32x4 z; z[0]=0.f; z[1]=0.f; z[2]=0.f; z[3]=0.f; return z; }

// ---------------- embedding ----------------
__global__ __launch_bounds__(256) void embed_kernel(const int* __restrict__ idx,
    const float* __restrict__ tok, const float* __restrict__ pos, float* __restrict__ x) {
  int row = blockIdx.x;                 // 0..B*T-1
  int t = row & (Tn - 1);
  int token = idx[row];
  const float* tr = tok + (size_t)token * Cn;
  const float* pr = pos + (size_t)t * Cn;
  float* xr = x + (size_t)row * Cn;
  for (int c = threadIdx.x; c < Cn; c += 256) xr[c] = tr[c] + pr[c];
}

// ---------------- layernorm -> bf16 ----------------
__global__ __launch_bounds__(256) void ln_kernel(const float* __restrict__ x,
    const float* __restrict__ gam, const float* __restrict__ bet, ushort_t* __restrict__ out) {
  int row = blockIdx.x;
  const float* xr = x + (size_t)row * Cn;
  float v[3]; float s = 0.f, s2 = 0.f;
  #pragma unroll
  for (int e = 0; e < 3; ++e) { float t = xr[threadIdx.x + e*256]; v[e] = t; s += t; s2 += t*t; }
  #pragma unroll
  for (int off = 32; off >= 1; off >>= 1) { s += __shfl_xor(s, off); s2 += __shfl_xor(s2, off); }
  __shared__ float red[8];
  int w = threadIdx.x >> 6;
  if ((threadIdx.x & 63) == 0) { red[w] = s; red[4 + w] = s2; }
  __syncthreads();
  s  = red[0] + red[1] + red[2] + red[3];
  s2 = red[4] + red[5] + red[6] + red[7];
  float mean = s * (1.f / Cn);
  float var  = s2 * (1.f / Cn) - mean * mean;
  float rstd = rsqrtf(var + 1e-5f);
  ushort_t* orow = out + (size_t)row * Cn;
  #pragma unroll
  for (int e = 0; e < 3; ++e) {
    int c = threadIdx.x + e*256;
    orow[c] = f2bf((v[e] - mean) * rstd * gam[c] + bet[c]);
  }
}

// ---------------- transpose + f32->bf16 weight conversion ----------------
// in: (K x N) f32 row-major.  out: (Npad x N-major) bf16, out[n*K+k]; n>=N zero-padded.
__global__ __launch_bounds__(256) void tcvt_kernel(const float* __restrict__ in,
    ushort_t* __restrict__ out, int K, int N, int Npad) {
  __shared__ float tile[32][33];
  int n0 = blockIdx.x * 32, k0 = blockIdx.y * 32;
  int tx = threadIdx.x, ty = threadIdx.y;
  #pragma unroll
  for (int r = 0; r < 4; ++r) {
    int k = k0 + ty + 8*r;
    int n = n0 + tx;
    tile[ty + 8*r][tx] = (n < N) ? in[(size_t)k * N + n] : 0.f;
  }
  __syncthreads();
  #pragma unroll
  for (int r = 0; r < 4; ++r) {
    int n = n0 + ty + 8*r;           // < Npad by grid construction
    out[(size_t)n * K + k0 + tx] = f2bf(tile[tx][ty + 8*r]);
  }
}

// ---------------- GEMM: C(MxN) = A(MxK) * W(KxN) [+bias][+res][gelu] ----------------
// A bf16 row-major (MxK); Bt bf16 = W^T row-major (N x K).
// MODE 0: out f32 = acc+bias ; MODE 1: out f32 = res+acc+bias ; MODE 2: out bf16 = gelu(acc+bias)
#define LROW 56
template<int MODE>
__global__ __launch_bounds__(256) void gemm_kernel(
    const ushort_t* __restrict__ A, const ushort_t* __restrict__ Bt,
    const float* __restrict__ bias, void* __restrict__ outp,
    const float* __restrict__ res, int M, int N, int K) {
  __shared__ ushort_t As[128 * LROW];
  __shared__ ushort_t Bs[128 * LROW];
  const int t = threadIdx.x;
  const int bn = blockIdx.x, bm = blockIdx.y;
  const int w = t >> 6, l = t & 63, lo = l & 15, g = l >> 4;
  const int wm = w >> 1, wn = w & 1;

  f32x4 acc[4][4];
  #pragma unroll
  for (int i = 0; i < 4; ++i)
    #pragma unroll
    for (int j = 0; j < 4; ++j) acc[i][j] = zero4();

  const int r0 = t >> 2;              // 0..63
  const int c0 = (t & 3) * 8;         // 0,8,16,24
  const size_t arow0 = (size_t)(bm * 128 + r0) * K;
  const size_t arow1 = (size_t)(bm * 128 + r0 + 64) * K;
  const size_t brow0 = (size_t)(bn * 128 + r0) * K;
  const size_t brow1 = (size_t)(bn * 128 + r0 + 64) * K;

  for (int k0 = 0; k0 < K; k0 += 32) {
    __syncthreads();
    *(int4v*)&As[(size_t)r0 * LROW + c0]        = *(const int4v*)&A[arow0 + k0 + c0];
    *(int4v*)&As[(size_t)(r0+64) * LROW + c0]   = *(const int4v*)&A[arow1 + k0 + c0];
    *(int4v*)&Bs[(size_t)r0 * LROW + c0]        = *(const int4v*)&Bt[brow0 + k0 + c0];
    *(int4v*)&Bs[(size_t)(r0+64) * LROW + c0]   = *(const int4v*)&Bt[brow1 + k0 + c0];
    __syncthreads();
    bf16x8 af[4], bfr[4];
    #pragma unroll
    for (int mi = 0; mi < 4; ++mi)
      af[mi] = *(const bf16x8*)&As[(size_t)(wm*64 + mi*16 + lo) * LROW + g*8];
    #pragma unroll
    for (int ni = 0; ni < 4; ++ni)
      bfr[ni] = *(const bf16x8*)&Bs[(size_t)(wn*64 + ni*16 + lo) * LROW + g*8];
    #pragma unroll
    for (int mi = 0; mi < 4; ++mi)
      #pragma unroll
      for (int ni = 0; ni < 4; ++ni)
        acc[mi][ni] = __builtin_amdgcn_mfma_f32_16x16x32_bf16(af[mi], bfr[ni], acc[mi][ni], 0, 0, 0);
  }

  #pragma unroll
  for (int mi = 0; mi < 4; ++mi) {
    #pragma unroll
    for (int ni = 0; ni < 4; ++ni) {
      int colg = bn*128 + wn*64 + ni*16 + lo;
      if (colg < N) {
        float bv = bias ? bias[colg] : 0.f;
        #pragma unroll
        for (int i = 0; i < 4; ++i) {
          int rowg = bm*128 + wm*64 + mi*16 + 4*g + i;
          size_t off = (size_t)rowg * N + colg;
          float vv = acc[mi][ni][i] + bv;
          if (MODE == 0) {
            ((float*)outp)[off] = vv;
          } else if (MODE == 1) {
            ((float*)outp)[off] = res[off] + vv;
          } else {
            float ge = 0.5f * vv * (1.f + erff(vv * 0.70710678118f));
            ((ushort_t*)outp)[off] = f2bf(ge);
          }
        }
      }
    }
  }
}

// ---------------- flash attention (causal), 1 wave / 16 q-rows ----------------
// qkv f32 [B*T][3C]; y bf16 [B*T][C]
__global__ __launch_bounds__(64) void attn_kernel(const float* __restrict__ qkv,
                                                  ushort_t* __restrict__ y) {
  const int l = threadIdx.x;
  const int lo = l & 15, g = l >> 4;
  const int qt = blockIdx.x;
  const int bh = blockIdx.y;
  const int b = bh / Hn, h = bh % Hn;
  const int q0 = qt * 16;
  const float* base = qkv + (size_t)b * Tn * (3*Cn);
  const float* Qp = base + h * 64;
  const float* Kp = base + Cn + h * 64;
  const float* Vp = base + 2*Cn + h * 64;
  __shared__ ushort_t P_lds[16 * 56];

  union U { bf16x8 v; ushort_t s[8]; };

  bf16x8 qf[2];
  {
    const float* qrow = Qp + (size_t)(q0 + lo) * (3*Cn);
    #pragma unroll
    for (int ch = 0; ch < 2; ++ch) {
      U u;
      #pragma unroll
      for (int bb = 0; bb < 8; ++bb) u.s[bb] = f2bf(qrow[ch*32 + g*8 + bb]);
      qf[ch] = u.v;
    }
  }

  f32x4 of[4];
  #pragma unroll
  for (int ch = 0; ch < 4; ++ch) of[ch] = zero4();
  float m = -1e30f, lsum = 0.f;
  const int nkv = q0 + 16;

  for (int kv0 = 0; kv0 < nkv; kv0 += 32) {
    float s8[8];
    #pragma unroll
    for (int sub = 0; sub < 2; ++sub) {
      int kvb = kv0 + 16*sub;
      if (kvb < nkv) {
        bf16x8 kf[2];
        const float* krow = Kp + (size_t)(kvb + lo) * (3*Cn);
        #pragma unroll
        for (int ch = 0; ch < 2; ++ch) {
          U u;
          #pragma unroll
          for (int bb = 0; bb < 8; ++bb) u.s[bb] = f2bf(krow[ch*32 + g*8 + bb]);
          kf[ch] = u.v;
        }
        f32x4 st = zero4();
        st = __builtin_amdgcn_mfma_f32_16x16x32_bf16(kf[0], qf[0], st, 0, 0, 0);
        st = __builtin_amdgcn_mfma_f32_16x16x32_bf16(kf[1], qf[1], st, 0, 0, 0);
        #pragma unroll
        for (int i = 0; i < 4; ++i) {
          int kvi = kvb + 4*g + i;
          float sv = st[i] * 0.125f;
          s8[sub*4 + i] = (kvi <= q0 + lo) ? sv : -1e30f;
        }
      } else {
        #pragma unroll
        for (int i = 0; i < 4; ++i) s8[sub*4 + i] = -1e30f;
      }
    }
    float tmax = s8[0];
    #pragma unroll
    for (int j = 1; j < 8; ++j) tmax = fmaxf(tmax, s8[j]);
    tmax = fmaxf(tmax, __shfl_xor(tmax, 16));
    tmax = fmaxf(tmax, __shfl_xor(tmax, 32));
    float newm = fmaxf(m, tmax);
    float resc = __expf(m - newm);
    float p8[8]; float psum = 0.f;
    #pragma unroll
    for (int j = 0; j < 8; ++j) { p8[j] = __expf(s8[j] - newm); psum += p8[j]; }
    psum += __shfl_xor(psum, 16);
    psum += __shfl_xor(psum, 32);
    lsum = lsum * resc + psum;
    m = newm;
    #pragma unroll
    for (int i = 0; i < 4; ++i) {
      float rs = __shfl(resc, 4*g + i);
      of[0][i] *= rs; of[1][i] *= rs; of[2][i] *= rs; of[3][i] *= rs;
    }
    // P -> LDS (verified D layout: value j belongs to kv_local = 16*(j>>2) + 4*g + (j&3))
    #pragma unroll
    for (int j = 0; j < 8; ++j) {
      int kvl = 16*(j>>2) + 4*g + (j&3);
      P_lds[lo*56 + kvl] = f2bf(p8[j]);
    }
    bf16x8 pa = *(const bf16x8*)&P_lds[lo*56 + g*8];
    #pragma unroll
    for (int ch = 0; ch < 4; ++ch) {
      U u;
      #pragma unroll
      for (int bb = 0; bb < 8; ++bb) {
        int kv = kv0 + 8*g + bb;
        float vv = (kv < nkv) ? Vp[(size_t)kv * (3*Cn) + ch*16 + lo] : 0.f;
        u.s[bb] = f2bf(vv);
      }
      of[ch] = __builtin_amdgcn_mfma_f32_16x16x32_bf16(pa, u.v, of[ch], 0, 0, 0);
    }
  }

  #pragma unroll
  for (int i = 0; i < 4; ++i) {
    float li = 1.f / __shfl(lsum, 4*g + i);
    of[0][i] *= li; of[1][i] *= li; of[2][i] *= li; of[3][i] *= li;
  }
  ushort_t* yb = y + ((size_t)b*Tn + q0) * Cn + h*64;
  #pragma unroll
  for (int ch = 0; ch < 4; ++ch)
    #pragma unroll
    for (int i = 0; i < 4; ++i)
      yb[(size_t)(4*g + i) * Cn + ch*16 + lo] = f2bf(of[ch][i]);
}

// ---------------- launch ----------------
extern "C" void kernel_launch(void* const* d_in, const int* in_sizes, int n_in,
                              void* d_out, int out_size, void* d_ws, size_t ws_size,
                              hipStream_t stream) {
  const int*   idx     = (const int*)d_in[0];
  const float* tok_emb = (const float*)d_in[1];
  const float* pos_emb = (const float*)d_in[2];
  const float* ln1_g   = (const float*)d_in[3];
  const float* ln1_b   = (const float*)d_in[4];
  const float* qkv_w   = (const float*)d_in[5];
  const float* qkv_b   = (const float*)d_in[6];
  const float* aproj_w = (const float*)d_in[7];
  const float* aproj_b = (const float*)d_in[8];
  const float* ln2_g   = (const float*)d_in[9];
  const float* ln2_b   = (const float*)d_in[10];
  const float* fc_w    = (const float*)d_in[11];
  const float* fc_b    = (const float*)d_in[12];
  const float* mproj_w = (const float*)d_in[13];
  const float* mproj_b = (const float*)d_in[14];
  const float* lnf_g   = (const float*)d_in[15];
  const float* lnf_b   = (const float*)d_in[16];
  const float* head_w  = (const float*)d_in[17];
  float* out = (float*)d_out;

  char* ws = (char*)d_ws;
  float*    x    = (float*)(ws);                                             // 12,582,912 B
  float*    qkvb = (float*)(ws + 12582912);                                  // 37,748,736 B
  ushort_t* hA   = (ushort_t*)(ws + 12582912 + 37748736);                    //  6,291,456 B
  ushort_t* hB   = (ushort_t*)(ws + 12582912 + 37748736 + 6291456);          // 25,165,824 B
  ushort_t* wT   = (ushort_t*)(ws + 12582912 + 37748736 + 6291456 + 25165824); // 77,266,944 B

  const int M = Bn * Tn;  // 4096
  dim3 tb(32, 8);

  embed_kernel<<<M, 256, 0, stream>>>(idx, tok_emb, pos_emb, x);
  for (int l = 0; l < Ln; ++l) {
    ln_kernel<<<M, 256, 0, stream>>>(x, ln1_g + l*Cn, ln1_b + l*Cn, hA);
    tcvt_kernel<<<dim3(2304/32, 768/32), tb, 0, stream>>>(qkv_w + (size_t)l*Cn*3*Cn, wT, 768, 2304, 2304);
    gemm_kernel<0><<<dim3(2304/128, M/128), 256, 0, stream>>>(hA, wT, qkv_b + (size_t)l*3*Cn, qkvb, nullptr, M, 2304, 768);
    attn_kernel<<<dim3(Tn/16, Bn*Hn), 64, 0, stream>>>(qkvb, hA);
    tcvt_kernel<<<dim3(768/32, 768/32), tb, 0, stream>>>(aproj_w + (size_t)l*Cn*Cn, wT, 768, 768, 768);
    gemm_kernel<1><<<dim3(768/128, M/128), 256, 0, stream>>>(hA, wT, aproj_b + (size_t)l*Cn, x, x, M, 768, 768);
    ln_kernel<<<M, 256, 0, stream>>>(x, ln2_g + l*Cn, ln2_b + l*Cn, hA);
    tcvt_kernel<<<dim3(3072/32, 768/32), tb, 0, stream>>>(fc_w + (size_t)l*Cn*4*Cn, wT, 768, 3072, 3072);
    gemm_kernel<2><<<dim3(3072/128, M/128), 256, 0, stream>>>(hA, wT, fc_b + (size_t)l*4*Cn, hB, nullptr, M, 3072, 768);
    tcvt_kernel<<<dim3(768/32, 3072/32), tb, 0, stream>>>(mproj_w + (size_t)l*4*Cn*Cn, wT, 3072, 768, 768);
    gemm_kernel<1><<<dim3(768/128, M/128), 256, 0, stream>>>(hB, wT, mproj_b + (size_t)l*Cn, x, x, M, 768, 3072);
  }
  ln_kernel<<<M, 256, 0, stream>>>(x, lnf_g, lnf_b, hA);
  tcvt_kernel<<<dim3(50304/32, 768/32), tb, 0, stream>>>(head_w, wT, 768, Vn, 50304);
  gemm_kernel<0><<<dim3((Vn+127)/128, M/128), 256, 0, stream>>>(hA, wT, nullptr, out, nullptr, M, Vn, 768);
}

// Round 2
// 2148.960 us; speedup vs baseline: 1.2452x; 1.2452x over previous
//
#include <hip/hip_runtime.h>
#include <cstdint>
#include <cstddef>

#define Tn 2048
#define Bn 2
#define Hn 12
#define Cn 768
#define Ln 4
#define Vn 50257

typedef unsigned short ushort_t;
typedef __attribute__((ext_vector_type(8))) __bf16 bf16x8;
typedef __attribute__((ext_vector_type(4))) float f32x4;

static constexpr size_t QKV_ELEMS = (size_t)Bn * Hn * Tn * 64;  // 3,145,728

__device__ inline unsigned short f2bf(float f) {
  unsigned int u = __float_as_uint(f);
  unsigned int r = (u + 0x7fffu + ((u >> 16) & 1u)) >> 16;
  return (unsigned short)r;
}

__device__ inline f32x4 zero4() { f32x4 z; z[0]=0.f; z[1]=0.f; z[2]=0.f; z[3]=0.f; return z; }

__device__ inline void gload_lds16(const ushort_t* g, ushort_t* l) {
  __builtin_amdgcn_global_load_lds(
      (const __attribute__((address_space(1))) void*)g,
      (__attribute__((address_space(3))) void*)l, 16, 0, 0);
}

// ---------------- embedding ----------------
__global__ __launch_bounds__(256) void embed_kernel(const int* __restrict__ idx,
    const float* __restrict__ tok, const float* __restrict__ pos, float* __restrict__ x) {
  int row = blockIdx.x;
  int t = row & (Tn - 1);
  int token = idx[row];
  const float* tr = tok + (size_t)token * Cn;
  const float* pr = pos + (size_t)t * Cn;
  float* xr = x + (size_t)row * Cn;
  for (int c = threadIdx.x; c < Cn; c += 256) xr[c] = tr[c] + pr[c];
}

// ---------------- layernorm -> bf16 ----------------
__global__ __launch_bounds__(256) void ln_kernel(const float* __restrict__ x,
    const float* __restrict__ gam, const float* __restrict__ bet, ushort_t* __restrict__ out) {
  int row = blockIdx.x;
  const float* xr = x + (size_t)row * Cn;
  float v[3]; float s = 0.f, s2 = 0.f;
  #pragma unroll
  for (int e = 0; e < 3; ++e) { float t = xr[threadIdx.x + e*256]; v[e] = t; s += t; s2 += t*t; }
  #pragma unroll
  for (int off = 32; off >= 1; off >>= 1) { s += __shfl_xor(s, off); s2 += __shfl_xor(s2, off); }
  __shared__ float red[8];
  int w = threadIdx.x >> 6;
  if ((threadIdx.x & 63) == 0) { red[w] = s; red[4 + w] = s2; }
  __syncthreads();
  s  = red[0] + red[1] + red[2] + red[3];
  s2 = red[4] + red[5] + red[6] + red[7];
  float mean = s * (1.f / Cn);
  float var  = s2 * (1.f / Cn) - mean * mean;
  float rstd = rsqrtf(var + 1e-5f);
  ushort_t* orow = out + (size_t)row * Cn;
  #pragma unroll
  for (int e = 0; e < 3; ++e) {
    int c = threadIdx.x + e*256;
    orow[c] = f2bf((v[e] - mean) * rstd * gam[c] + bet[c]);
  }
}

// ---------------- transpose + f32->bf16 weight conversion ----------------
__global__ __launch_bounds__(256) void tcvt_kernel(const float* __restrict__ in,
    ushort_t* __restrict__ out, int K, int N, int Npad) {
  __shared__ float tile[32][33];
  int n0 = blockIdx.x * 32, k0 = blockIdx.y * 32;
  int tx = threadIdx.x, ty = threadIdx.y;
  #pragma unroll
  for (int r = 0; r < 4; ++r) {
    int k = k0 + ty + 8*r;
    int n = n0 + tx;
    tile[ty + 8*r][tx] = (n < N) ? in[(size_t)k * N + n] : 0.f;
  }
  __syncthreads();
  #pragma unroll
  for (int r = 0; r < 4; ++r) {
    int n = n0 + ty + 8*r;
    out[(size_t)n * K + k0 + tx] = f2bf(tile[tx][ty + 8*r]);
  }
}

// ---------------- GEMM (m97 structure): C(MxN) = A(MxK) * Bt^T ----------------
// A bf16 row-major (MxK); Bt bf16 (N x K) row-major.
// MODE 0: f32 = acc+bias ; 1: f32 = res+acc+bias ; 2: bf16 = gelu(acc+bias)
// MODE 3: qkv scatter -> q [B,H,T,64] (x0.125), k [B,H,T,64], v^T [B,H,64,T], all bf16
template<int MODE, int TM>
__global__ __launch_bounds__(256) void gemm_kernel(
    const ushort_t* __restrict__ A, const ushort_t* __restrict__ Bt,
    const float* __restrict__ bias, void* __restrict__ outp,
    const float* __restrict__ res, int M, int N, int K) {
  constexpr int MI = TM / 32;                  // mfma-tiles per wave in M
  __shared__ ushort_t As[TM * 32];
  __shared__ ushort_t Bs[128 * 32];
  const int t = threadIdx.x;
  const int bn = blockIdx.x, bm = blockIdx.y;
  const int w = t >> 6, l = t & 63, lo = l & 15, g = l >> 4;
  const int wm = w >> 1, wn = w & 1;

  f32x4 acc[MI][4];
  #pragma unroll
  for (int i = 0; i < MI; ++i)
    #pragma unroll
    for (int j = 0; j < 4; ++j) acc[i][j] = zero4();

  const int srow = t >> 2;
  const int scol = (t & 3) * 8;
  const ushort_t* gA = A  + (size_t)(bm * TM  + srow) * K + scol;
  const ushort_t* gB = Bt + (size_t)(bn * 128 + srow) * K + scol;
  ushort_t* lA = As + w * 512;   // wave-uniform LDS base (w*1024 bytes)
  ushort_t* lB = Bs + w * 512;

  for (int k0 = 0; k0 < K; k0 += 32) {
    __syncthreads();
    gload_lds16(gA + k0, lA);
    if (TM == 128) gload_lds16(gA + (size_t)64 * K + k0, lA + 2048);
    gload_lds16(gB + k0, lB);
    gload_lds16(gB + (size_t)64 * K + k0, lB + 2048);
    __syncthreads();
    bf16x8 af[MI], bfr[4];
    #pragma unroll
    for (int mi = 0; mi < MI; ++mi)
      af[mi] = *(const bf16x8*)&As[(size_t)(wm*(TM/2) + mi*16 + lo) * 32 + g*8];
    #pragma unroll
    for (int ni = 0; ni < 4; ++ni)
      bfr[ni] = *(const bf16x8*)&Bs[(size_t)(wn*64 + ni*16 + lo) * 32 + g*8];
    #pragma unroll
    for (int mi = 0; mi < MI; ++mi)
      #pragma unroll
      for (int ni = 0; ni < 4; ++ni)
        acc[mi][ni] = __builtin_amdgcn_mfma_f32_16x16x32_bf16(af[mi], bfr[ni], acc[mi][ni], 0, 0, 0);
  }

  #pragma unroll
  for (int mi = 0; mi < MI; ++mi) {
    #pragma unroll
    for (int ni = 0; ni < 4; ++ni) {
      int colg = bn*128 + wn*64 + ni*16 + lo;
      if (colg < N) {
        float bv = bias ? bias[colg] : 0.f;
        #pragma unroll
        for (int i = 0; i < 4; ++i) {
          int rowg = bm*TM + wm*(TM/2) + mi*16 + 4*g + i;
          float vv = acc[mi][ni][i] + bv;
          if (MODE == 0) {
            ((float*)outp)[(size_t)rowg * N + colg] = vv;
          } else if (MODE == 1) {
            size_t off = (size_t)rowg * N + colg;
            ((float*)outp)[off] = res[off] + vv;
          } else if (MODE == 2) {
            float ge = 0.5f * vv * (1.f + erff(vv * 0.70710678118f));
            ((ushort_t*)outp)[(size_t)rowg * N + colg] = f2bf(ge);
          } else {
            int which = colg / Cn;
            int rem = colg - which * Cn;
            int h = rem >> 6, d = rem & 63;
            int b = rowg >> 11, tt = rowg & (Tn - 1);
            ushort_t* qb = (ushort_t*)outp;
            size_t bh = (size_t)(b * Hn + h);
            if (which == 0)      qb[(bh*Tn + tt)*64 + d] = f2bf(vv * 0.125f);
            else if (which == 1) qb[QKV_ELEMS + (bh*Tn + tt)*64 + d] = f2bf(vv);
            else                 qb[2*QKV_ELEMS + (bh*64 + d)*Tn + tt] = f2bf(vv);
          }
        }
      }
    }
  }
}

// ---------------- flash attention (causal), 1 wave / 16 q-rows ----------------
// qh [B,H,T,64] bf16 (pre-scaled); kh [B,H,T,64]; vT [B,H,64,T]; y bf16 [B*T][C]
__global__ __launch_bounds__(64) void attn_kernel(const ushort_t* __restrict__ qkvh,
                                                  ushort_t* __restrict__ y) {
  const int l = threadIdx.x;
  const int lo = l & 15, g = l >> 4;
  const int qt = blockIdx.x;
  const int bh = blockIdx.y;
  const int b = bh / Hn, h = bh % Hn;
  const int q0 = qt * 16;
  const ushort_t* Qp = qkvh + (size_t)bh * Tn * 64;
  const ushort_t* Kp = qkvh + QKV_ELEMS + (size_t)bh * Tn * 64;
  const ushort_t* Vt = qkvh + 2*QKV_ELEMS + (size_t)bh * 64 * Tn;
  __shared__ ushort_t P_lds[16 * 56];

  bf16x8 qf[2];
  #pragma unroll
  for (int ch = 0; ch < 2; ++ch)
    qf[ch] = *(const bf16x8*)&Qp[(size_t)(q0 + lo) * 64 + ch*32 + g*8];

  f32x4 of[4];
  #pragma unroll
  for (int ch = 0; ch < 4; ++ch) of[ch] = zero4();
  float m = -1e30f, lsum = 0.f;
  const int nkv = q0 + 16;

  for (int kv0 = 0; kv0 < nkv; kv0 += 32) {
    float s8[8];
    #pragma unroll
    for (int sub = 0; sub < 2; ++sub) {
      int kvb = kv0 + 16*sub;
      bf16x8 kf[2];
      #pragma unroll
      for (int ch = 0; ch < 2; ++ch)
        kf[ch] = *(const bf16x8*)&Kp[(size_t)(kvb + lo) * 64 + ch*32 + g*8];
      f32x4 st = zero4();
      st = __builtin_amdgcn_mfma_f32_16x16x32_bf16(kf[0], qf[0], st, 0, 0, 0);
      st = __builtin_amdgcn_mfma_f32_16x16x32_bf16(kf[1], qf[1], st, 0, 0, 0);
      #pragma unroll
      for (int i = 0; i < 4; ++i) {
        int kvi = kvb + 4*g + i;
        s8[sub*4 + i] = (kvi <= q0 + lo) ? st[i] : -1e30f;
      }
    }
    float tmax = s8[0];
    #pragma unroll
    for (int j = 1; j < 8; ++j) tmax = fmaxf(tmax, s8[j]);
    tmax = fmaxf(tmax, __shfl_xor(tmax, 16));
    tmax = fmaxf(tmax, __shfl_xor(tmax, 32));
    float newm = fmaxf(m, tmax);
    float resc = __expf(m - newm);
    float p8[8]; float psum = 0.f;
    #pragma unroll
    for (int j = 0; j < 8; ++j) { p8[j] = __expf(s8[j] - newm); psum += p8[j]; }
    psum += __shfl_xor(psum, 16);
    psum += __shfl_xor(psum, 32);
    lsum = lsum * resc + psum;
    m = newm;
    #pragma unroll
    for (int i = 0; i < 4; ++i) {
      float rs = __shfl(resc, 4*g + i);
      of[0][i] *= rs; of[1][i] *= rs; of[2][i] *= rs; of[3][i] *= rs;
    }
    #pragma unroll
    for (int j = 0; j < 8; ++j) {
      int kvl = 16*(j>>2) + 4*g + (j&3);
      P_lds[lo*56 + kvl] = f2bf(p8[j]);
    }
    bf16x8 pa = *(const bf16x8*)&P_lds[lo*56 + g*8];
    #pragma unroll
    for (int ch = 0; ch < 4; ++ch) {
      bf16x8 vf = *(const bf16x8*)&Vt[(size_t)(ch*16 + lo) * Tn + kv0 + g*8];
      of[ch] = __builtin_amdgcn_mfma_f32_16x16x32_bf16(pa, vf, of[ch], 0, 0, 0);
    }
  }

  #pragma unroll
  for (int i = 0; i < 4; ++i) {
    float li = 1.f / __shfl(lsum, 4*g + i);
    of[0][i] *= li; of[1][i] *= li; of[2][i] *= li; of[3][i] *= li;
  }
  ushort_t* yb = y + ((size_t)b*Tn + q0) * Cn + h*64;
  #pragma unroll
  for (int ch = 0; ch < 4; ++ch)
    #pragma unroll
    for (int i = 0; i < 4; ++i)
      yb[(size_t)(4*g + i) * Cn + ch*16 + lo] = f2bf(of[ch][i]);
}

// ---------------- launch ----------------
extern "C" void kernel_launch(void* const* d_in, const int* in_sizes, int n_in,
                              void* d_out, int out_size, void* d_ws, size_t ws_size,
                              hipStream_t stream) {
  const int*   idx     = (const int*)d_in[0];
  const float* tok_emb = (const float*)d_in[1];
  const float* pos_emb = (const float*)d_in[2];
  const float* ln1_g   = (const float*)d_in[3];
  const float* ln1_b   = (const float*)d_in[4];
  const float* qkv_w   = (const float*)d_in[5];
  const float* qkv_b   = (const float*)d_in[6];
  const float* aproj_w = (const float*)d_in[7];
  const float* aproj_b = (const float*)d_in[8];
  const float* ln2_g   = (const float*)d_in[9];
  const float* ln2_b   = (const float*)d_in[10];
  const float* fc_w    = (const float*)d_in[11];
  const float* fc_b    = (const float*)d_in[12];
  const float* mproj_w = (const float*)d_in[13];
  const float* mproj_b = (const float*)d_in[14];
  const float* lnf_g   = (const float*)d_in[15];
  const float* lnf_b   = (const float*)d_in[16];
  const float* head_w  = (const float*)d_in[17];
  float* out = (float*)d_out;

  char* ws = (char*)d_ws;
  float*    x    = (float*)(ws);                         // 12,582,912 B
  ushort_t* hA   = (ushort_t*)(ws + 12582912);           //  6,291,456 B
  ushort_t* hB   = (ushort_t*)(ws + 18874368);           // 25,165,824 B
  ushort_t* qkvh = (ushort_t*)(ws + 44040192);           // 18,874,368 B (q,k,vT)
  ushort_t* wT   = (ushort_t*)(ws + 62914560);           // 77,266,944 B

  const int M = Bn * Tn;  // 4096
  dim3 tb(32, 8);

  embed_kernel<<<M, 256, 0, stream>>>(idx, tok_emb, pos_emb, x);
  for (int l = 0; l < Ln; ++l) {
    ln_kernel<<<M, 256, 0, stream>>>(x, ln1_g + l*Cn, ln1_b + l*Cn, hA);
    tcvt_kernel<<<dim3(2304/32, 768/32), tb, 0, stream>>>(qkv_w + (size_t)l*Cn*3*Cn, wT, 768, 2304, 2304);
    gemm_kernel<3,128><<<dim3(2304/128, M/128), 256, 0, stream>>>(hA, wT, qkv_b + (size_t)l*3*Cn, qkvh, nullptr, M, 2304, 768);
    attn_kernel<<<dim3(Tn/16, Bn*Hn), 64, 0, stream>>>(qkvh, hA);
    tcvt_kernel<<<dim3(768/32, 768/32), tb, 0, stream>>>(aproj_w + (size_t)l*Cn*Cn, wT, 768, 768, 768);
    gemm_kernel<1,64><<<dim3(768/128, M/64), 256, 0, stream>>>(hA, wT, aproj_b + (size_t)l*Cn, x, x, M, 768, 768);
    ln_kernel<<<M, 256, 0, stream>>>(x, ln2_g + l*Cn, ln2_b + l*Cn, hA);
    tcvt_kernel<<<dim3(3072/32, 768/32), tb, 0, stream>>>(fc_w + (size_t)l*Cn*4*Cn, wT, 768, 3072, 3072);
    gemm_kernel<2,128><<<dim3(3072/128, M/128), 256, 0, stream>>>(hA, wT, fc_b + (size_t)l*4*Cn, hB, nullptr, M, 3072, 768);
    tcvt_kernel<<<dim3(768/32, 3072/32), tb, 0, stream>>>(mproj_w + (size_t)l*4*Cn*Cn, wT, 3072, 768, 768);
    gemm_kernel<1,64><<<dim3(768/128, M/64), 256, 0, stream>>>(hB, wT, mproj_b + (size_t)l*Cn, x, x, M, 768, 3072);
  }
  ln_kernel<<<M, 256, 0, stream>>>(x, lnf_g, lnf_b, hA);
  tcvt_kernel<<<dim3(50304/32, 768/32), tb, 0, stream>>>(head_w, wT, 768, Vn, 50304);
  gemm_kernel<0,128><<<dim3((Vn+127)/128, M/128), 256, 0, stream>>>(hA, wT, nullptr, out, nullptr, M, Vn, 768);
}

// Round 4
// 1918.506 us; speedup vs baseline: 1.3947x; 1.1201x over previous
//
#include <hip/hip_runtime.h>
#include <cstdint>
#include <cstddef>

#define Tn 2048
#define Bn 2
#define Hn 12
#define Cn 768
#define Ln 4
#define Vn 50257

typedef unsigned short ushort_t;
typedef __attribute__((ext_vector_type(8))) __bf16 bf16x8;
typedef __attribute__((ext_vector_type(8))) unsigned short u16x8;
typedef __attribute__((ext_vector_type(4))) float f32x4;

static constexpr size_t QKV_ELEMS = (size_t)Bn * Hn * Tn * 64;  // 3,145,728

__device__ inline unsigned short f2bf(float f) {
  unsigned int u = __float_as_uint(f);
  unsigned int r = (u + 0x7fffu + ((u >> 16) & 1u)) >> 16;
  return (unsigned short)r;
}

__device__ inline f32x4 zero4() { f32x4 z; z[0]=0.f; z[1]=0.f; z[2]=0.f; z[3]=0.f; return z; }

__device__ inline void gload_lds16(const ushort_t* g, ushort_t* l) {
  __builtin_amdgcn_global_load_lds(
      (const __attribute__((address_space(1))) void*)g,
      (__attribute__((address_space(3))) void*)l, 16, 0, 0);
}

// bijective XCD-chunked swizzle (m204): consecutive remapped ids stay on one XCD
__device__ inline int swz_lin() {
  int nbm = gridDim.x;
  int lin = blockIdx.y * nbm + blockIdx.x;
  int nwg = nbm * gridDim.y;
  int q = nwg >> 3, r = nwg & 7, x = lin & 7, p = lin >> 3;
  return (x < r ? x * (q + 1) : r * (q + 1) + (x - r) * q) + p;
}

// ---------------- embedding ----------------
__global__ __launch_bounds__(256) void embed_kernel(const int* __restrict__ idx,
    const float* __restrict__ tok, const float* __restrict__ pos, float* __restrict__ x) {
  int row = blockIdx.x;
  int t = row & (Tn - 1);
  int token = idx[row];
  const float* tr = tok + (size_t)token * Cn;
  const float* pr = pos + (size_t)t * Cn;
  float* xr = x + (size_t)row * Cn;
  for (int c = threadIdx.x; c < Cn; c += 256) xr[c] = tr[c] + pr[c];
}

// ---------------- layernorm -> bf16 ----------------
__global__ __launch_bounds__(256) void ln_kernel(const float* __restrict__ x,
    const float* __restrict__ gam, const float* __restrict__ bet, ushort_t* __restrict__ out) {
  int row = blockIdx.x;
  const float* xr = x + (size_t)row * Cn;
  float v[3]; float s = 0.f, s2 = 0.f;
  #pragma unroll
  for (int e = 0; e < 3; ++e) { float t = xr[threadIdx.x + e*256]; v[e] = t; s += t; s2 += t*t; }
  #pragma unroll
  for (int off = 32; off >= 1; off >>= 1) { s += __shfl_xor(s, off); s2 += __shfl_xor(s2, off); }
  __shared__ float red[8];
  int w = threadIdx.x >> 6;
  if ((threadIdx.x & 63) == 0) { red[w] = s; red[4 + w] = s2; }
  __syncthreads();
  s  = red[0] + red[1] + red[2] + red[3];
  s2 = red[4] + red[5] + red[6] + red[7];
  float mean = s * (1.f / Cn);
  float var  = s2 * (1.f / Cn) - mean * mean;
  float rstd = rsqrtf(var + 1e-5f);
  ushort_t* orow = out + (size_t)row * Cn;
  #pragma unroll
  for (int e = 0; e < 3; ++e) {
    int c = threadIdx.x + e*256;
    orow[c] = f2bf((v[e] - mean) * rstd * gam[c] + bet[c]);
  }
}

// ---------------- transpose + f32->bf16 weight conversion ----------------
__global__ __launch_bounds__(256) void tcvt_kernel(const float* __restrict__ in,
    ushort_t* __restrict__ out, int K, int N, int Npad) {
  __shared__ float tile[32][33];
  int n0 = blockIdx.x * 32, k0 = blockIdx.y * 32;
  int tx = threadIdx.x, ty = threadIdx.y;
  #pragma unroll
  for (int r = 0; r < 4; ++r) {
    int k = k0 + ty + 8*r;
    int n = n0 + tx;
    tile[ty + 8*r][tx] = (n < N) ? in[(size_t)k * N + n] : 0.f;
  }
  __syncthreads();
  #pragma unroll
  for (int r = 0; r < 4; ++r) {
    int n = n0 + ty + 8*r;
    out[(size_t)n * K + k0 + tx] = f2bf(tile[tx][ty + 8*r]);
  }
}

// ---------------- bf16 64x64 tile transpose: [BH,T,64] -> [BH,64,T] ----------------
__global__ __launch_bounds__(256) void vtrans_kernel(const ushort_t* __restrict__ vin,
                                                     ushort_t* __restrict__ vout) {
  __shared__ ushort_t tile[64][65];
  int t0 = blockIdx.x * 64;
  size_t bh = blockIdx.y;
  const ushort_t* src = vin + (bh * Tn + t0) * 64;
  int row = threadIdx.x >> 2, c0 = (threadIdx.x & 3) * 16;
  u16x8 a = *(const u16x8*)&src[(size_t)row * 64 + c0];
  u16x8 b = *(const u16x8*)&src[(size_t)row * 64 + c0 + 8];
  #pragma unroll
  for (int j = 0; j < 8; ++j) { tile[row][c0 + j] = a[j]; tile[row][c0 + 8 + j] = b[j]; }
  __syncthreads();
  int d = threadIdx.x >> 2, tq = (threadIdx.x & 3) * 16;
  u16x8 o0, o1;
  #pragma unroll
  for (int j = 0; j < 8; ++j) { o0[j] = tile[tq + j][d]; o1[j] = tile[tq + 8 + j][d]; }
  ushort_t* dst = vout + (bh * 64 + d) * Tn + t0 + tq;
  *(u16x8*)&dst[0] = o0;
  *(u16x8*)&dst[8] = o1;
}

// ---------------- GEMM (m97 structure + XCD swizzle): C = A * Bt^T ----------------
// MODE 0: f32 = acc+bias ; 1: f32 = res+acc+bias ; 2: bf16 = gelu(acc+bias)
// MODE 3: q [B,H,T,64] (x0.125), k [B,H,T,64], v [B,H,T,64] (coalesced; transposed later)
template<int MODE, int TM>
__global__ __launch_bounds__(256) void gemm_kernel(
    const ushort_t* __restrict__ A, const ushort_t* __restrict__ Bt,
    const float* __restrict__ bias, void* __restrict__ outp,
    const float* __restrict__ res, int M, int N, int K) {
  constexpr int MI = TM / 32;
  __shared__ ushort_t As[TM * 32];
  __shared__ ushort_t Bs[128 * 32];
  const int t = threadIdx.x;
  int nl = swz_lin();
  const int bm = nl % gridDim.x;       // bm fast within an XCD chunk -> B-panel reuse
  const int bn = nl / gridDim.x;
  const int w = t >> 6, l = t & 63, lo = l & 15, g = l >> 4;
  const int wm = w >> 1, wn = w & 1;

  f32x4 acc[MI][4];
  #pragma unroll
  for (int i = 0; i < MI; ++i)
    #pragma unroll
    for (int j = 0; j < 4; ++j) acc[i][j] = zero4();

  const int srow = t >> 2;
  const int scol = (t & 3) * 8;
  const ushort_t* gA = A  + (size_t)(bm * TM  + srow) * K + scol;
  const ushort_t* gB = Bt + (size_t)(bn * 128 + srow) * K + scol;
  ushort_t* lA = As + w * 512;
  ushort_t* lB = Bs + w * 512;

  for (int k0 = 0; k0 < K; k0 += 32) {
    __syncthreads();
    gload_lds16(gA + k0, lA);
    if (TM == 128) gload_lds16(gA + (size_t)64 * K + k0, lA + 2048);
    gload_lds16(gB + k0, lB);
    gload_lds16(gB + (size_t)64 * K + k0, lB + 2048);
    __syncthreads();
    bf16x8 af[MI], bfr[4];
    #pragma unroll
    for (int mi = 0; mi < MI; ++mi)
      af[mi] = *(const bf16x8*)&As[(size_t)(wm*(TM/2) + mi*16 + lo) * 32 + g*8];
    #pragma unroll
    for (int ni = 0; ni < 4; ++ni)
      bfr[ni] = *(const bf16x8*)&Bs[(size_t)(wn*64 + ni*16 + lo) * 32 + g*8];
    #pragma unroll
    for (int mi = 0; mi < MI; ++mi)
      #pragma unroll
      for (int ni = 0; ni < 4; ++ni)
        acc[mi][ni] = __builtin_amdgcn_mfma_f32_16x16x32_bf16(af[mi], bfr[ni], acc[mi][ni], 0, 0, 0);
  }

  #pragma unroll
  for (int mi = 0; mi < MI; ++mi) {
    #pragma unroll
    for (int ni = 0; ni < 4; ++ni) {
      int colg = bn*128 + wn*64 + ni*16 + lo;
      if (colg < N) {
        float bv = bias ? bias[colg] : 0.f;
        #pragma unroll
        for (int i = 0; i < 4; ++i) {
          int rowg = bm*TM + wm*(TM/2) + mi*16 + 4*g + i;
          float vv = acc[mi][ni][i] + bv;
          if (MODE == 0) {
            ((float*)outp)[(size_t)rowg * N + colg] = vv;
          } else if (MODE == 1) {
            size_t off = (size_t)rowg * N + colg;
            ((float*)outp)[off] = res[off] + vv;
          } else if (MODE == 2) {
            float ge = 0.5f * vv * (1.f + erff(vv * 0.70710678118f));
            ((ushort_t*)outp)[(size_t)rowg * N + colg] = f2bf(ge);
          } else {
            int which = colg / Cn;
            int rem = colg - which * Cn;
            int h = rem >> 6, d = rem & 63;
            int b = rowg >> 11, tt = rowg & (Tn - 1);
            ushort_t* qb = (ushort_t*)outp;
            size_t bh = (size_t)(b * Hn + h);
            size_t off = (bh * Tn + tt) * 64 + d;
            if (which == 0)      qb[off] = f2bf(vv * 0.125f);
            else if (which == 1) qb[QKV_ELEMS + off] = f2bf(vv);
            else                 qb[3*QKV_ELEMS + off] = f2bf(vv);   // staging; vtrans -> 2*QKV
          }
        }
      }
    }
  }
}

// ---------------- flash attention (causal), 1 wave / 16 q-rows, no LDS ----------------
__global__ __launch_bounds__(64) void attn_kernel(const ushort_t* __restrict__ qkvh,
                                                  ushort_t* __restrict__ y) {
  const int l = threadIdx.x;
  const int lo = l & 15, g = l >> 4;
  int nl = swz_lin();
  const int qt = nl & 127;             // gridDim.x = 128 (qt fast within XCD chunk)
  const int bh = nl >> 7;
  const int b = bh / Hn, h = bh % Hn;
  const int q0 = qt * 16;
  const ushort_t* Qp = qkvh + (size_t)bh * Tn * 64;
  const ushort_t* Kp = qkvh + QKV_ELEMS + (size_t)bh * Tn * 64;
  const ushort_t* Vt = qkvh + 2*QKV_ELEMS + (size_t)bh * 64 * Tn;

  bf16x8 qf[2];
  #pragma unroll
  for (int ch = 0; ch < 2; ++ch)
    qf[ch] = *(const bf16x8*)&Qp[(size_t)(q0 + lo) * 64 + ch*32 + g*8];

  f32x4 of[4];
  #pragma unroll
  for (int ch = 0; ch < 4; ++ch) of[ch] = zero4();
  float m = -1e30f, lsum = 0.f;
  const int nkv = q0 + 16;
  const bool ghi = (g >= 2);
  const int lg2 = (g & 1) * 32;

  for (int kv0 = 0; kv0 < nkv; kv0 += 32) {
    // V fragments first: global latency hides under QK^T + softmax
    bf16x8 vf[4];
    #pragma unroll
    for (int ch = 0; ch < 4; ++ch)
      vf[ch] = *(const bf16x8*)&Vt[(size_t)(ch*16 + lo) * Tn + kv0 + g*8];

    float s8[8];
    #pragma unroll
    for (int sub = 0; sub < 2; ++sub) {
      int kvb = kv0 + 16*sub;
      bf16x8 kf[2];
      #pragma unroll
      for (int ch = 0; ch < 2; ++ch)
        kf[ch] = *(const bf16x8*)&Kp[(size_t)(kvb + lo) * 64 + ch*32 + g*8];
      f32x4 st = zero4();
      st = __builtin_amdgcn_mfma_f32_16x16x32_bf16(kf[0], qf[0], st, 0, 0, 0);
      st = __builtin_amdgcn_mfma_f32_16x16x32_bf16(kf[1], qf[1], st, 0, 0, 0);
      #pragma unroll
      for (int i = 0; i < 4; ++i) {
        int kvi = kvb + 4*g + i;
        s8[sub*4 + i] = (kvi <= q0 + lo) ? st[i] : -1e30f;
      }
    }
    float tmax = s8[0];
    #pragma unroll
    for (int j = 1; j < 8; ++j) tmax = fmaxf(tmax, s8[j]);
    tmax = fmaxf(tmax, __shfl_xor(tmax, 16));
    tmax = fmaxf(tmax, __shfl_xor(tmax, 32));
    float newm = fmaxf(m, tmax);
    float resc = __expf(m - newm);
    float p8[8]; float psum = 0.f;
    #pragma unroll
    for (int j = 0; j < 8; ++j) { p8[j] = __expf(s8[j] - newm); psum += p8[j]; }
    psum += __shfl_xor(psum, 16);
    psum += __shfl_xor(psum, 32);
    lsum = lsum * resc + psum;
    m = newm;
    #pragma unroll
    for (int i = 0; i < 4; ++i) {
      float rs = __shfl(resc, 4*g + i);
      of[0][i] *= rs; of[1][i] *= rs; of[2][i] *= rs; of[3][i] *= rs;
    }
    // in-register P redistribution.
    // lane(lo,g') holds P[q=lo][kv_local = 16*(j>>2) + 4*g' + (j&3)] at p8[j].
    // A-frag target: lane(lo,g) word j = {kv_local 8g+2j, 8g+2j+1}.
    //   source lane g' = 2*(g&1) + (j>>1); word index (g>=2?2:0)+(j&1).
    // Shuffle BOTH candidate words (selection index compile-time uniform),
    // then select by the DESTINATION's g — source-lane-predicate bug fixed.
    unsigned int q4[4];
    #pragma unroll
    for (int c = 0; c < 4; ++c)
      q4[c] = (unsigned int)f2bf(p8[2*c]) | ((unsigned int)f2bf(p8[2*c+1]) << 16);
    union { unsigned int wv[4]; bf16x8 v; } pu;
    #pragma unroll
    for (int j = 0; j < 4; ++j) {
      int srcLane = lo + lg2 + ((j >> 1) << 4);
      unsigned int lo_w = (unsigned int)__shfl((int)q4[j & 1], srcLane);
      unsigned int hi_w = (unsigned int)__shfl((int)q4[2 + (j & 1)], srcLane);
      pu.wv[j] = ghi ? hi_w : lo_w;
    }
    #pragma unroll
    for (int ch = 0; ch < 4; ++ch)
      of[ch] = __builtin_amdgcn_mfma_f32_16x16x32_bf16(pu.v, vf[ch], of[ch], 0, 0, 0);
  }

  #pragma unroll
  for (int i = 0; i < 4; ++i) {
    float li = 1.f / __shfl(lsum, 4*g + i);
    of[0][i] *= li; of[1][i] *= li; of[2][i] *= li; of[3][i] *= li;
  }
  ushort_t* yb = y + ((size_t)b*Tn + q0) * Cn + h*64;
  #pragma unroll
  for (int ch = 0; ch < 4; ++ch)
    #pragma unroll
    for (int i = 0; i < 4; ++i)
      yb[(size_t)(4*g + i) * Cn + ch*16 + lo] = f2bf(of[ch][i]);
}

// ---------------- launch ----------------
extern "C" void kernel_launch(void* const* d_in, const int* in_sizes, int n_in,
                              void* d_out, int out_size, void* d_ws, size_t ws_size,
                              hipStream_t stream) {
  const int*   idx     = (const int*)d_in[0];
  const float* tok_emb = (const float*)d_in[1];
  const float* pos_emb = (const float*)d_in[2];
  const float* ln1_g   = (const float*)d_in[3];
  const float* ln1_b   = (const float*)d_in[4];
  const float* qkv_w   = (const float*)d_in[5];
  const float* qkv_b   = (const float*)d_in[6];
  const float* aproj_w = (const float*)d_in[7];
  const float* aproj_b = (const float*)d_in[8];
  const float* ln2_g   = (const float*)d_in[9];
  const float* ln2_b   = (const float*)d_in[10];
  const float* fc_w    = (const float*)d_in[11];
  const float* fc_b    = (const float*)d_in[12];
  const float* mproj_w = (const float*)d_in[13];
  const float* mproj_b = (const float*)d_in[14];
  const float* lnf_g   = (const float*)d_in[15];
  const float* lnf_b   = (const float*)d_in[16];
  const float* head_w  = (const float*)d_in[17];
  float* out = (float*)d_out;

  char* ws = (char*)d_ws;
  float*    x    = (float*)(ws);                         // 12,582,912 B
  ushort_t* hA   = (ushort_t*)(ws + 12582912);           //  6,291,456 B
  ushort_t* hB   = (ushort_t*)(ws + 18874368);           // 25,165,824 B
  ushort_t* qkvh = (ushort_t*)(ws + 44040192);           // 25,165,824 B (q,k,vT,vtmp)
  ushort_t* wT   = (ushort_t*)(ws + 69206016);           // 77,266,944 B

  const int M = Bn * Tn;  // 4096
  dim3 tb(32, 8);

  embed_kernel<<<M, 256, 0, stream>>>(idx, tok_emb, pos_emb, x);
  for (int l = 0; l < Ln; ++l) {
    ln_kernel<<<M, 256, 0, stream>>>(x, ln1_g + l*Cn, ln1_b + l*Cn, hA);
    tcvt_kernel<<<dim3(2304/32, 768/32), tb, 0, stream>>>(qkv_w + (size_t)l*Cn*3*Cn, wT, 768, 2304, 2304);
    gemm_kernel<3,128><<<dim3(M/128, 2304/128), 256, 0, stream>>>(hA, wT, qkv_b + (size_t)l*3*Cn, qkvh, nullptr, M, 2304, 768);
    vtrans_kernel<<<dim3(Tn/64, Bn*Hn), 256, 0, stream>>>(qkvh + 3*QKV_ELEMS, qkvh + 2*QKV_ELEMS);
    attn_kernel<<<dim3(128, Bn*Hn), 64, 0, stream>>>(qkvh, hA);
    tcvt_kernel<<<dim3(768/32, 768/32), tb, 0, stream>>>(aproj_w + (size_t)l*Cn*Cn, wT, 768, 768, 768);
    gemm_kernel<1,64><<<dim3(M/64, 768/128), 256, 0, stream>>>(hA, wT, aproj_b + (size_t)l*Cn, x, x, M, 768, 768);
    ln_kernel<<<M, 256, 0, stream>>>(x, ln2_g + l*Cn, ln2_b + l*Cn, hA);
    tcvt_kernel<<<dim3(3072/32, 768/32), tb, 0, stream>>>(fc_w + (size_t)l*Cn*4*Cn, wT, 768, 3072, 3072);
    gemm_kernel<2,128><<<dim3(M/128, 3072/128), 256, 0, stream>>>(hA, wT, fc_b + (size_t)l*4*Cn, hB, nullptr, M, 3072, 768);
    tcvt_kernel<<<dim3(768/32, 3072/32), tb, 0, stream>>>(mproj_w + (size_t)l*4*Cn*Cn, wT, 3072, 768, 768);
    gemm_kernel<1,64><<<dim3(M/64, 768/128), 256, 0, stream>>>(hB, wT, mproj_b + (size_t)l*Cn, x, x, M, 768, 3072);
  }
  ln_kernel<<<M, 256, 0, stream>>>(x, lnf_g, lnf_b, hA);
  tcvt_kernel<<<dim3(50304/32, 768/32), tb, 0, stream>>>(head_w, wT, 768, Vn, 50304);
  gemm_kernel<0,128><<<dim3(M/128, 50304/128), 256, 0, stream>>>(hA, wT, nullptr, out, nullptr, M, Vn, 768);
}

// Round 5
// 1851.561 us; speedup vs baseline: 1.4451x; 1.0362x over previous
//
#include <hip/hip_runtime.h>
#include <cstdint>
#include <cstddef>

#define Tn 2048
#define Bn 2
#define Hn 12
#define Cn 768
#define Ln 4
#define Vn 50257

typedef unsigned short ushort_t;
typedef __attribute__((ext_vector_type(8))) __bf16 bf16x8;
typedef __attribute__((ext_vector_type(8))) unsigned short u16x8;
typedef __attribute__((ext_vector_type(4))) float f32x4;

static constexpr size_t QKV_ELEMS = (size_t)Bn * Hn * Tn * 64;  // 3,145,728

__device__ inline unsigned short f2bf(float f) {
  unsigned int u = __float_as_uint(f);
  unsigned int r = (u + 0x7fffu + ((u >> 16) & 1u)) >> 16;
  return (unsigned short)r;
}

__device__ inline f32x4 zero4() { f32x4 z; z[0]=0.f; z[1]=0.f; z[2]=0.f; z[3]=0.f; return z; }

__device__ inline void gload_lds16(const ushort_t* g, ushort_t* l) {
  __builtin_amdgcn_global_load_lds(
      (const __attribute__((address_space(1))) void*)g,
      (__attribute__((address_space(3))) void*)l, 16, 0, 0);
}

// bijective XCD-chunked swizzle (m204)
__device__ inline int swz_lin() {
  int nbm = gridDim.x;
  int lin = blockIdx.y * nbm + blockIdx.x;
  int nwg = nbm * gridDim.y;
  int q = nwg >> 3, r = nwg & 7, x = lin & 7, p = lin >> 3;
  return (x < r ? x * (q + 1) : r * (q + 1) + (x - r) * q) + p;
}

// ---------------- embedding ----------------
__global__ __launch_bounds__(256) void embed_kernel(const int* __restrict__ idx,
    const float* __restrict__ tok, const float* __restrict__ pos, float* __restrict__ x) {
  int row = blockIdx.x;
  int t = row & (Tn - 1);
  int token = idx[row];
  const float* tr = tok + (size_t)token * Cn;
  const float* pr = pos + (size_t)t * Cn;
  float* xr = x + (size_t)row * Cn;
  for (int c = threadIdx.x; c < Cn; c += 256) xr[c] = tr[c] + pr[c];
}

// ---------------- layernorm -> bf16 ----------------
__global__ __launch_bounds__(256) void ln_kernel(const float* __restrict__ x,
    const float* __restrict__ gam, const float* __restrict__ bet, ushort_t* __restrict__ out) {
  int row = blockIdx.x;
  const float* xr = x + (size_t)row * Cn;
  float v[3]; float s = 0.f, s2 = 0.f;
  #pragma unroll
  for (int e = 0; e < 3; ++e) { float t = xr[threadIdx.x + e*256]; v[e] = t; s += t; s2 += t*t; }
  #pragma unroll
  for (int off = 32; off >= 1; off >>= 1) { s += __shfl_xor(s, off); s2 += __shfl_xor(s2, off); }
  __shared__ float red[8];
  int w = threadIdx.x >> 6;
  if ((threadIdx.x & 63) == 0) { red[w] = s; red[4 + w] = s2; }
  __syncthreads();
  s  = red[0] + red[1] + red[2] + red[3];
  s2 = red[4] + red[5] + red[6] + red[7];
  float mean = s * (1.f / Cn);
  float var  = s2 * (1.f / Cn) - mean * mean;
  float rstd = rsqrtf(var + 1e-5f);
  ushort_t* orow = out + (size_t)row * Cn;
  #pragma unroll
  for (int e = 0; e < 3; ++e) {
    int c = threadIdx.x + e*256;
    orow[c] = f2bf((v[e] - mean) * rstd * gam[c] + bet[c]);
  }
}

// ---------------- transpose + f32->bf16 weight conversion ----------------
__global__ __launch_bounds__(256) void tcvt_kernel(const float* __restrict__ in,
    ushort_t* __restrict__ out, int K, int N, int Npad) {
  __shared__ float tile[32][33];
  int n0 = blockIdx.x * 32, k0 = blockIdx.y * 32;
  int tx = threadIdx.x, ty = threadIdx.y;
  #pragma unroll
  for (int r = 0; r < 4; ++r) {
    int k = k0 + ty + 8*r;
    int n = n0 + tx;
    tile[ty + 8*r][tx] = (n < N) ? in[(size_t)k * N + n] : 0.f;
  }
  __syncthreads();
  #pragma unroll
  for (int r = 0; r < 4; ++r) {
    int n = n0 + ty + 8*r;
    out[(size_t)n * K + k0 + tx] = f2bf(tile[tx][ty + 8*r]);
  }
}

// ---------------- bf16 64x64 tile transpose: [BH,T,64] -> [BH,64,T] ----------------
__global__ __launch_bounds__(256) void vtrans_kernel(const ushort_t* __restrict__ vin,
                                                     ushort_t* __restrict__ vout) {
  __shared__ ushort_t tile[64][65];
  int t0 = blockIdx.x * 64;
  size_t bh = blockIdx.y;
  const ushort_t* src = vin + (bh * Tn + t0) * 64;
  int row = threadIdx.x >> 2, c0 = (threadIdx.x & 3) * 16;
  u16x8 a = *(const u16x8*)&src[(size_t)row * 64 + c0];
  u16x8 b = *(const u16x8*)&src[(size_t)row * 64 + c0 + 8];
  #pragma unroll
  for (int j = 0; j < 8; ++j) { tile[row][c0 + j] = a[j]; tile[row][c0 + 8 + j] = b[j]; }
  __syncthreads();
  int d = threadIdx.x >> 2, tq = (threadIdx.x & 3) * 16;
  u16x8 o0, o1;
  #pragma unroll
  for (int j = 0; j < 8; ++j) { o0[j] = tile[tq + j][d]; o1[j] = tile[tq + 8 + j][d]; }
  ushort_t* dst = vout + (bh * 64 + d) * Tn + t0 + tq;
  *(u16x8*)&dst[0] = o0;
  *(u16x8*)&dst[8] = o1;
}

// ---------------- GEMM: 2-phase pipelined K-loop + 2D-super-tiled XCD mapping ----------
// MODE 0: f32 = acc+bias ; 1: f32 = res+acc+bias ; 2: bf16 = gelu(acc+bias)
// MODE 3: q [B,H,T,64] (x0.125), k [B,H,T,64], v [B,H,T,64] (coalesced; transposed later)
template<int MODE, int TM>
__global__ __launch_bounds__(256) void gemm_kernel(
    const ushort_t* __restrict__ A, const ushort_t* __restrict__ Bt,
    const float* __restrict__ bias, void* __restrict__ outp,
    const float* __restrict__ res, int M, int N, int K) {
  constexpr int MI = TM / 32;
  constexpr int ABUF = TM * 32;
  __shared__ ushort_t As[2 * ABUF];
  __shared__ ushort_t Bs[2 * 4096];
  const int t = threadIdx.x;

  // mapping: XCD-chunked seq; within: bm fast in group of G=8, then bn, then bm-group.
  // per-XCD hot set = G A-panels (1.57MB, L2-resident) + streaming B panels.
  int bm, bn;
  {
    int seq = swz_lin();
    const int G = 8;
    int NBN = gridDim.y;
    int gsz = G * NBN;
    int grp = seq / gsz;
    int t2 = seq - grp * gsz;
    bn = t2 / G;
    bm = grp * G + (t2 - bn * G);
  }
  const int w = t >> 6, l = t & 63, lo = l & 15, g = l >> 4;
  const int wm = w >> 1, wn = w & 1;

  f32x4 acc[MI][4];
  #pragma unroll
  for (int i = 0; i < MI; ++i)
    #pragma unroll
    for (int j = 0; j < 4; ++j) acc[i][j] = zero4();

  const int srow = t >> 2;
  const int scol = (t & 3) * 8;
  const ushort_t* gA = A  + (size_t)(bm * TM  + srow) * K + scol;
  const ushort_t* gB = Bt + (size_t)(bn * 128 + srow) * K + scol;
  ushort_t* lA = As + w * 512;
  ushort_t* lB = Bs + w * 512;

  auto stage = [&](int buf, int k0) {
    gload_lds16(gA + k0, lA + buf * ABUF);
    if (TM == 128) gload_lds16(gA + (size_t)64 * K + k0, lA + buf * ABUF + 2048);
    gload_lds16(gB + k0, lB + buf * 4096);
    gload_lds16(gB + (size_t)64 * K + k0, lB + buf * 4096 + 2048);
  };
  auto compute = [&](int buf) {
    const ushort_t* as = As + buf * ABUF;
    const ushort_t* bs = Bs + buf * 4096;
    bf16x8 af[MI], bfr[4];
    #pragma unroll
    for (int mi = 0; mi < MI; ++mi)
      af[mi] = *(const bf16x8*)&as[(size_t)(wm*(TM/2) + mi*16 + lo) * 32 + g*8];
    #pragma unroll
    for (int ni = 0; ni < 4; ++ni)
      bfr[ni] = *(const bf16x8*)&bs[(size_t)(wn*64 + ni*16 + lo) * 32 + g*8];
    #pragma unroll
    for (int mi = 0; mi < MI; ++mi)
      #pragma unroll
      for (int ni = 0; ni < 4; ++ni)
        acc[mi][ni] = __builtin_amdgcn_mfma_f32_16x16x32_bf16(af[mi], bfr[ni], acc[mi][ni], 0, 0, 0);
  };

  const int NK = K >> 5;           // 24 for K=768
  stage(0, 0);
  __syncthreads();                 // drains vmcnt(0): tile 0 ready
  for (int kk = 0; kk < NK - 1; ++kk) {
    stage((kk + 1) & 1, (kk + 1) << 5);  // issue next tile BEFORE compute
    compute(kk & 1);                     // MFMA phase hides load latency
    __syncthreads();                     // one vmcnt-drain barrier per tile
  }
  compute((NK - 1) & 1);

  #pragma unroll
  for (int mi = 0; mi < MI; ++mi) {
    #pragma unroll
    for (int ni = 0; ni < 4; ++ni) {
      int colg = bn*128 + wn*64 + ni*16 + lo;
      if (colg < N) {
        float bv = bias ? bias[colg] : 0.f;
        #pragma unroll
        for (int i = 0; i < 4; ++i) {
          int rowg = bm*TM + wm*(TM/2) + mi*16 + 4*g + i;
          float vv = acc[mi][ni][i] + bv;
          if (MODE == 0) {
            ((float*)outp)[(size_t)rowg * N + colg] = vv;
          } else if (MODE == 1) {
            size_t off = (size_t)rowg * N + colg;
            ((float*)outp)[off] = res[off] + vv;
          } else if (MODE == 2) {
            float ge = 0.5f * vv * (1.f + erff(vv * 0.70710678118f));
            ((ushort_t*)outp)[(size_t)rowg * N + colg] = f2bf(ge);
          } else {
            int which = colg / Cn;
            int rem = colg - which * Cn;
            int h = rem >> 6, d = rem & 63;
            int b = rowg >> 11, tt = rowg & (Tn - 1);
            ushort_t* qb = (ushort_t*)outp;
            size_t bh = (size_t)(b * Hn + h);
            size_t off = (bh * Tn + tt) * 64 + d;
            if (which == 0)      qb[off] = f2bf(vv * 0.125f);
            else if (which == 1) qb[QKV_ELEMS + off] = f2bf(vv);
            else                 qb[3*QKV_ELEMS + off] = f2bf(vv);   // staging; vtrans -> 2*QKV
          }
        }
      }
    }
  }
}

// ---------------- flash attention (causal), 1 wave / 16 q-rows, no LDS ----------------
__global__ __launch_bounds__(64) void attn_kernel(const ushort_t* __restrict__ qkvh,
                                                  ushort_t* __restrict__ y) {
  const int l = threadIdx.x;
  const int lo = l & 15, g = l >> 4;
  int nl = swz_lin();
  const int qt = nl & 127;             // gridDim.x = 128 (qt fast within XCD chunk)
  const int bh = nl >> 7;
  const int b = bh / Hn, h = bh % Hn;
  const int q0 = qt * 16;
  const ushort_t* Qp = qkvh + (size_t)bh * Tn * 64;
  const ushort_t* Kp = qkvh + QKV_ELEMS + (size_t)bh * Tn * 64;
  const ushort_t* Vt = qkvh + 2*QKV_ELEMS + (size_t)bh * 64 * Tn;

  bf16x8 qf[2];
  #pragma unroll
  for (int ch = 0; ch < 2; ++ch)
    qf[ch] = *(const bf16x8*)&Qp[(size_t)(q0 + lo) * 64 + ch*32 + g*8];

  f32x4 of[4];
  #pragma unroll
  for (int ch = 0; ch < 4; ++ch) of[ch] = zero4();
  float m = -1e30f, lsum = 0.f;
  const int nkv = q0 + 16;
  const bool ghi = (g >= 2);
  const int lg2 = (g & 1) * 32;

  for (int kv0 = 0; kv0 < nkv; kv0 += 32) {
    bf16x8 vf[4];
    #pragma unroll
    for (int ch = 0; ch < 4; ++ch)
      vf[ch] = *(const bf16x8*)&Vt[(size_t)(ch*16 + lo) * Tn + kv0 + g*8];

    float s8[8];
    #pragma unroll
    for (int sub = 0; sub < 2; ++sub) {
      int kvb = kv0 + 16*sub;
      bf16x8 kf[2];
      #pragma unroll
      for (int ch = 0; ch < 2; ++ch)
        kf[ch] = *(const bf16x8*)&Kp[(size_t)(kvb + lo) * 64 + ch*32 + g*8];
      f32x4 st = zero4();
      st = __builtin_amdgcn_mfma_f32_16x16x32_bf16(kf[0], qf[0], st, 0, 0, 0);
      st = __builtin_amdgcn_mfma_f32_16x16x32_bf16(kf[1], qf[1], st, 0, 0, 0);
      #pragma unroll
      for (int i = 0; i < 4; ++i) {
        int kvi = kvb + 4*g + i;
        s8[sub*4 + i] = (kvi <= q0 + lo) ? st[i] : -1e30f;
      }
    }
    float tmax = s8[0];
    #pragma unroll
    for (int j = 1; j < 8; ++j) tmax = fmaxf(tmax, s8[j]);
    tmax = fmaxf(tmax, __shfl_xor(tmax, 16));
    tmax = fmaxf(tmax, __shfl_xor(tmax, 32));
    float newm = fmaxf(m, tmax);
    float resc = __expf(m - newm);
    float p8[8]; float psum = 0.f;
    #pragma unroll
    for (int j = 0; j < 8; ++j) { p8[j] = __expf(s8[j] - newm); psum += p8[j]; }
    psum += __shfl_xor(psum, 16);
    psum += __shfl_xor(psum, 32);
    lsum = lsum * resc + psum;
    m = newm;
    #pragma unroll
    for (int i = 0; i < 4; ++i) {
      float rs = __shfl(resc, 4*g + i);
      of[0][i] *= rs; of[1][i] *= rs; of[2][i] *= rs; of[3][i] *= rs;
    }
    // in-register P redistribution: shuffle BOTH candidate words, select by DEST g.
    unsigned int q4[4];
    #pragma unroll
    for (int c = 0; c < 4; ++c)
      q4[c] = (unsigned int)f2bf(p8[2*c]) | ((unsigned int)f2bf(p8[2*c+1]) << 16);
    union { unsigned int wv[4]; bf16x8 v; } pu;
    #pragma unroll
    for (int j = 0; j < 4; ++j) {
      int srcLane = lo + lg2 + ((j >> 1) << 4);
      unsigned int lo_w = (unsigned int)__shfl((int)q4[j & 1], srcLane);
      unsigned int hi_w = (unsigned int)__shfl((int)q4[2 + (j & 1)], srcLane);
      pu.wv[j] = ghi ? hi_w : lo_w;
    }
    #pragma unroll
    for (int ch = 0; ch < 4; ++ch)
      of[ch] = __builtin_amdgcn_mfma_f32_16x16x32_bf16(pu.v, vf[ch], of[ch], 0, 0, 0);
  }

  #pragma unroll
  for (int i = 0; i < 4; ++i) {
    float li = 1.f / __shfl(lsum, 4*g + i);
    of[0][i] *= li; of[1][i] *= li; of[2][i] *= li; of[3][i] *= li;
  }
  ushort_t* yb = y + ((size_t)b*Tn + q0) * Cn + h*64;
  #pragma unroll
  for (int ch = 0; ch < 4; ++ch)
    #pragma unroll
    for (int i = 0; i < 4; ++i)
      yb[(size_t)(4*g + i) * Cn + ch*16 + lo] = f2bf(of[ch][i]);
}

// ---------------- launch ----------------
extern "C" void kernel_launch(void* const* d_in, const int* in_sizes, int n_in,
                              void* d_out, int out_size, void* d_ws, size_t ws_size,
                              hipStream_t stream) {
  const int*   idx     = (const int*)d_in[0];
  const float* tok_emb = (const float*)d_in[1];
  const float* pos_emb = (const float*)d_in[2];
  const float* ln1_g   = (const float*)d_in[3];
  const float* ln1_b   = (const float*)d_in[4];
  const float* qkv_w   = (const float*)d_in[5];
  const float* qkv_b   = (const float*)d_in[6];
  const float* aproj_w = (const float*)d_in[7];
  const float* aproj_b = (const float*)d_in[8];
  const float* ln2_g   = (const float*)d_in[9];
  const float* ln2_b   = (const float*)d_in[10];
  const float* fc_w    = (const float*)d_in[11];
  const float* fc_b    = (const float*)d_in[12];
  const float* mproj_w = (const float*)d_in[13];
  const float* mproj_b = (const float*)d_in[14];
  const float* lnf_g   = (const float*)d_in[15];
  const float* lnf_b   = (const float*)d_in[16];
  const float* head_w  = (const float*)d_in[17];
  float* out = (float*)d_out;

  char* ws = (char*)d_ws;
  float*    x    = (float*)(ws);                         // 12,582,912 B
  ushort_t* hA   = (ushort_t*)(ws + 12582912);           //  6,291,456 B
  ushort_t* hB   = (ushort_t*)(ws + 18874368);           // 25,165,824 B
  ushort_t* qkvh = (ushort_t*)(ws + 44040192);           // 25,165,824 B (q,k,vT,vtmp)
  ushort_t* wT   = (ushort_t*)(ws + 69206016);           // 77,266,944 B

  const int M = Bn * Tn;  // 4096
  dim3 tb(32, 8);

  embed_kernel<<<M, 256, 0, stream>>>(idx, tok_emb, pos_emb, x);
  for (int l = 0; l < Ln; ++l) {
    ln_kernel<<<M, 256, 0, stream>>>(x, ln1_g + l*Cn, ln1_b + l*Cn, hA);
    tcvt_kernel<<<dim3(2304/32, 768/32), tb, 0, stream>>>(qkv_w + (size_t)l*Cn*3*Cn, wT, 768, 2304, 2304);
    gemm_kernel<3,128><<<dim3(M/128, 2304/128), 256, 0, stream>>>(hA, wT, qkv_b + (size_t)l*3*Cn, qkvh, nullptr, M, 2304, 768);
    vtrans_kernel<<<dim3(Tn/64, Bn*Hn), 256, 0, stream>>>(qkvh + 3*QKV_ELEMS, qkvh + 2*QKV_ELEMS);
    attn_kernel<<<dim3(128, Bn*Hn), 64, 0, stream>>>(qkvh, hA);
    tcvt_kernel<<<dim3(768/32, 768/32), tb, 0, stream>>>(aproj_w + (size_t)l*Cn*Cn, wT, 768, 768, 768);
    gemm_kernel<1,64><<<dim3(M/64, 768/128), 256, 0, stream>>>(hA, wT, aproj_b + (size_t)l*Cn, x, x, M, 768, 768);
    ln_kernel<<<M, 256, 0, stream>>>(x, ln2_g + l*Cn, ln2_b + l*Cn, hA);
    tcvt_kernel<<<dim3(3072/32, 768/32), tb, 0, stream>>>(fc_w + (size_t)l*Cn*4*Cn, wT, 768, 3072, 3072);
    gemm_kernel<2,128><<<dim3(M/128, 3072/128), 256, 0, stream>>>(hA, wT, fc_b + (size_t)l*4*Cn, hB, nullptr, M, 3072, 768);
    tcvt_kernel<<<dim3(768/32, 3072/32), tb, 0, stream>>>(mproj_w + (size_t)l*4*Cn*Cn, wT, 3072, 768, 768);
    gemm_kernel<1,64><<<dim3(M/64, 768/128), 256, 0, stream>>>(hB, wT, mproj_b + (size_t)l*Cn, x, x, M, 768, 3072);
  }
  ln_kernel<<<M, 256, 0, stream>>>(x, lnf_g, lnf_b, hA);
  tcvt_kernel<<<dim3(50304/32, 768/32), tb, 0, stream>>>(head_w, wT, 768, Vn, 50304);
  gemm_kernel<0,128><<<dim3(M/128, 50304/128), 256, 0, stream>>>(hA, wT, nullptr, out, nullptr, M, Vn, 768);
}